// Round 16
// baseline (171.320 us; speedup 1.0000x reference)
//
#include <hip/hip_runtime.h>
#include <hip/hip_bf16.h>

#define DM 1024
#define NH 16
#define HD 64
#define B_ 2
#define S_ 2048
#define M_ (B_*S_)   // 4096

typedef __attribute__((ext_vector_type(8))) short bf16x8;
typedef __attribute__((ext_vector_type(4))) float f32x4;
typedef __attribute__((ext_vector_type(4))) unsigned uint32x4;
typedef __attribute__((ext_vector_type(2))) unsigned uint32x2;

__device__ __forceinline__ float bf2f(ushort u) {
  union { unsigned u32; float f; } c; c.u32 = ((unsigned)u) << 16; return c.f;
}
__device__ __forceinline__ ushort f2bf(float f) {
  union { float f; unsigned u32; } c; c.f = f;
  unsigned u = c.u32;
  unsigned r = (u + 0x7fffu + ((u >> 16) & 1u)) >> 16;
  return (ushort)r;
}
__device__ __forceinline__ unsigned fbits(float f) {
  union { float f; unsigned u; } c; c.f = f; return c.u;
}

// async global->LDS, 16 B per lane; LDS dest = wave-uniform base + lane*16
__device__ __forceinline__ void async16(const ushort* g, ushort* l) {
  __builtin_amdgcn_global_load_lds((const __attribute__((address_space(1))) void*)g,
                                   (__attribute__((address_space(3))) void*)l, 16, 0, 0);
}

// gfx950 cross-lane swaps via BUILTINS (not inline asm): permlane has a VALU-write ->
// permlane-read hazard requiring compiler-inserted wait states; the hazard recognizer
// can't see into inline asm (v9/v10 raw-asm miscompute; v11 builtins fixed it).
__device__ __forceinline__ void pswap32(unsigned& a, unsigned& b) {
  uint32x2 r = __builtin_amdgcn_permlane32_swap(a, b, false, false);
  a = r[0]; b = r[1];
}
__device__ __forceinline__ void pswap16(unsigned& a, unsigned& b) {
  uint32x2 r = __builtin_amdgcn_permlane16_swap(a, b, false, false);
  a = r[0]; b = r[1];
}

// ---- fused prep: z<4 -> fp32 W[k][n] -> bf16 Wt[n][k]; z==4 -> fp32 x -> bf16 ----
__global__ void cvt_prep(const float* __restrict__ x, const float* __restrict__ W0,
                         const float* __restrict__ W1, const float* __restrict__ W2,
                         const float* __restrict__ W3, ushort* __restrict__ wt,
                         ushort* __restrict__ xb) {
  __shared__ float tile[64][65];
  int z = blockIdx.z;
  int tx = threadIdx.x, ty = threadIdx.y;   // block (64,4)
  if (z == 4) {
    int tid = ty * 64 + tx;
    size_t base4 = ((size_t)blockIdx.y * 16 + blockIdx.x) * 4096;  // float4 units
    const float4* xv = (const float4*)x;
    ushort4* ov = (ushort4*)xb;
    #pragma unroll
    for (int k = 0; k < 16; ++k) {
      float4 v = xv[base4 + k * 256 + tid];
      ushort4 o;
      o.x = f2bf(v.x); o.y = f2bf(v.y); o.z = f2bf(v.z); o.w = f2bf(v.w);
      ov[base4 + k * 256 + tid] = o;
    }
    return;
  }
  const float* W = (z == 0) ? W0 : (z == 1) ? W1 : (z == 2) ? W2 : W3;
  ushort* Wt = wt + (size_t)z * (DM * DM);
  int c0 = blockIdx.x * 64, r0 = blockIdx.y * 64;
  #pragma unroll
  for (int i = ty; i < 64; i += 4) tile[i][tx] = W[(size_t)(r0 + i) * DM + c0 + tx];
  __syncthreads();
  #pragma unroll
  for (int i = ty; i < 64; i += 4) Wt[(size_t)(c0 + i) * DM + r0 + tx] = f2bf(tile[tx][i]);
}

// ---------------- MFMA GEMM body (used by gemm_out, MODE 0 only) ----------------
template <int MODE, int BN>
__device__ __forceinline__ void gemm_body(const ushort* __restrict__ A,
                                          const ushort* __restrict__ Bt,
                                          ushort* __restrict__ Cb,
                                          float* __restrict__ Cf,
                                          ushort* As, ushort* Bs, ushort* Ts) {
  const int K = DM;
  constexpr int CN = BN / 32;                   // n-frags per wave
  int m0 = blockIdx.y * 128;
  int n0 = blockIdx.x * BN;
  int t = threadIdx.x;
  int lane = t & 63, wave = t >> 6;
  int wm = (wave >> 1) * 64, wn = (wave & 1) * (BN / 2);
  int lrow = lane & 15, quad = lane >> 4;

  int Ra = wave * 32;                           // A rows staged by this wave
  int Rb = wave * (BN / 4);                     // B rows staged by this wave
  int srow = lane >> 2, scol = (lane & 3) * 8;  // per-lane 16B chunk within 16-row group

  f32x4 acc[4][CN];
  #pragma unroll
  for (int r = 0; r < 4; ++r)
    #pragma unroll
    for (int c = 0; c < CN; ++c) acc[r][c] = (f32x4){0.f, 0.f, 0.f, 0.f};

  for (int k0 = 0; k0 < K; k0 += 32) {
    const ushort* ga = A + (size_t)(m0 + Ra + srow) * K + k0 + scol;
    const ushort* gb = Bt + (size_t)(n0 + Rb + srow) * K + k0 + scol;
    async16(ga,          As + Ra * 32);
    async16(ga + 16 * K, As + (Ra + 16) * 32);
    async16(gb,          Bs + Rb * 32);
    if (BN == 128) async16(gb + 16 * K, Bs + (Rb + 16) * 32);
    __syncthreads();

    bf16x8 af[4], bfr[CN];
    #pragma unroll
    for (int r = 0; r < 4; ++r)
      af[r] = *(const bf16x8*)(As + (wm + r * 16 + lrow) * 32 + quad * 8);
    #pragma unroll
    for (int c = 0; c < CN; ++c)
      bfr[c] = *(const bf16x8*)(Bs + (wn + c * 16 + lrow) * 32 + quad * 8);
    #pragma unroll
    for (int r = 0; r < 4; ++r)
      #pragma unroll
      for (int c = 0; c < CN; ++c)
        acc[r][c] = __builtin_amdgcn_mfma_f32_16x16x32_bf16(af[r], bfr[c], acc[r][c], 0, 0, 0);
    __syncthreads();
  }

  // epilogue: C/D layout col=lane&15, row=quad*4+e
  #pragma unroll
  for (int r = 0; r < 4; ++r) {
    #pragma unroll
    for (int c = 0; c < CN; ++c) {
      #pragma unroll
      for (int e = 0; e < 4; ++e) {
        int m = m0 + wm + r * 16 + quad * 4 + e;
        int n = n0 + wn + c * 16 + lrow;
        if (MODE == 0) {
          Cf[(size_t)m * DM + n] = acc[r][c][e];
        }
      }
    }
  }
}

// ---------------- fused QKV GEMM ----------------
// v19: one block computes Q, K, V for its 128(M)x64(N) tile. A staged ONCE per K-step
// and af[4] read once, reused against 3 weight panels (24 MFMA / 10 ds_read vs 16/8,
// and 512 block-K-walks vs 768). Fixes v18 profile's FETCH 35.9MB (A re-fetched 3x by
// the z-sliced dispatch; footprint is ~14MB). Epilogues are the proven MODE1 (Q,K) and
// MODE2 V^T-transpose (z=2); BN=64 == HD so each n-tile is exactly one head (h2=n0>>6).
// acc 3x4x2 f32x4 = 96 VGPR -> ~150 total; (256,2) so no forced spill (v8 lesson).
// LDS 20.5 KB: As[0:4096) Bs0[4096:6144) Bs1[6144:8192) Bs2[8192:10240); Ts aliases
// [0:4608) after the K-loop (guarded by barriers, same pattern as before).
__global__ __launch_bounds__(256, 2) void gemm_qkv(const ushort* __restrict__ A,
                                                   const ushort* __restrict__ wt,
                                                   ushort* __restrict__ qkv) {
  __shared__ __align__(16) ushort smem[10240];
  ushort* As = smem;
  ushort* Ts = smem;
  const int K = DM;
  int m0 = blockIdx.y * 128;
  int n0 = blockIdx.x * 64;
  int t = threadIdx.x;
  int lane = t & 63, wave = t >> 6;
  int wm = (wave >> 1) * 64, wn = (wave & 1) * 32;
  int lrow = lane & 15, quad = lane >> 4;
  int Ra = wave * 32;                           // A rows staged by this wave
  int Rb = wave * 16;                           // B rows staged by this wave (per z)
  int srow = lane >> 2, scol = (lane & 3) * 8;

  f32x4 acc[3][4][2];
  #pragma unroll
  for (int z = 0; z < 3; ++z)
    #pragma unroll
    for (int r = 0; r < 4; ++r)
      #pragma unroll
      for (int c = 0; c < 2; ++c) acc[z][r][c] = (f32x4){0.f, 0.f, 0.f, 0.f};

  for (int k0 = 0; k0 < K; k0 += 32) {
    const ushort* ga = A + (size_t)(m0 + Ra + srow) * K + k0 + scol;
    async16(ga,          As + Ra * 32);
    async16(ga + 16 * K, As + (Ra + 16) * 32);
    #pragma unroll
    for (int z = 0; z < 3; ++z) {
      const ushort* gb = wt + (size_t)z * (DM * DM) + (size_t)(n0 + Rb + srow) * K + k0 + scol;
      async16(gb, smem + 4096 + z * 2048 + Rb * 32);
    }
    __syncthreads();

    bf16x8 af[4];
    #pragma unroll
    for (int r = 0; r < 4; ++r)
      af[r] = *(const bf16x8*)(As + (wm + r * 16 + lrow) * 32 + quad * 8);
    #pragma unroll
    for (int z = 0; z < 3; ++z) {
      bf16x8 bfr[2];
      #pragma unroll
      for (int c = 0; c < 2; ++c)
        bfr[c] = *(const bf16x8*)(smem + 4096 + z * 2048 + (wn + c * 16 + lrow) * 32 + quad * 8);
      #pragma unroll
      for (int r = 0; r < 4; ++r)
        #pragma unroll
        for (int c = 0; c < 2; ++c)
          acc[z][r][c] = __builtin_amdgcn_mfma_f32_16x16x32_bf16(af[r], bfr[c], acc[z][r][c], 0, 0, 0);
    }
    __syncthreads();
  }

  // ---- epilogue z=0,1 (Q,K): head layout [b,h,s,d] ----
  #pragma unroll
  for (int z = 0; z < 2; ++z) {
    ushort* Cz = qkv + (size_t)z * ((size_t)M_ * DM);
    #pragma unroll
    for (int r = 0; r < 4; ++r) {
      #pragma unroll
      for (int c = 0; c < 2; ++c) {
        #pragma unroll
        for (int e = 0; e < 4; ++e) {
          int m = m0 + wm + r * 16 + quad * 4 + e;
          int n = n0 + wn + c * 16 + lrow;
          int b = m >> 11, s = m & 2047, h = n >> 6, d = n & 63;
          Cz[(((size_t)(b * NH + h)) * S_ + s) * HD + d] = f2bf(acc[z][r][c][e]);
        }
      }
    }
  }

  // ---- epilogue z=2 (V): V^T [b,h,d,s] via LDS transpose, two half-passes ----
  {
    ushort* Cb = qkv + (size_t)2 * ((size_t)M_ * DM);
    int bb = m0 >> 11;
    int s0base = m0 & 2047;
    int h2 = n0 >> 6;
    #pragma unroll
    for (int H = 0; H < 2; ++H) {
      __syncthreads();            // Ts reuse guard (and As/Bs death guard on H=0)
      if ((wave >> 1) == H) {
        #pragma unroll
        for (int r = 0; r < 4; ++r)
          #pragma unroll
          for (int c = 0; c < 2; ++c) {
            uint2 pk;
            pk.x = (unsigned)f2bf(acc[2][r][c][0]) | ((unsigned)f2bf(acc[2][r][c][1]) << 16);
            pk.y = (unsigned)f2bf(acc[2][r][c][2]) | ((unsigned)f2bf(acc[2][r][c][3]) << 16);
            *(uint2*)(Ts + (wn + c * 16 + lrow) * 72 + r * 16 + quad * 4) = pk;
          }
      }
      __syncthreads();
      #pragma unroll
      for (int i = 0; i < 2; ++i) {
        int id = t + i * 256;            // 0..511
        int nn = id >> 3, col = (id & 7) * 8;
        uint4 v = *(const uint4*)(Ts + nn * 72 + col);
        size_t dst = (((size_t)(bb * NH + h2)) * HD + nn) * (size_t)S_ + s0base + H * 64 + col;
        *(uint4*)(Cb + dst) = v;
      }
    }
  }
}

// 128x64 tiles -> grid 512, 12 KB LDS, 3 blocks/CU target
__global__ __launch_bounds__(256, 3) void gemm_out(const ushort* __restrict__ A,
                                                   const ushort* __restrict__ wt,
                                                   float* __restrict__ C) {
  __shared__ __align__(16) ushort As[128 * 32];
  __shared__ __align__(16) ushort Bs[64 * 32];
  gemm_body<0, 64>(A, wt, nullptr, C, As, Bs, nullptr);
}

// ---------------- MFMA flash attention v18 (unchanged): single-barrier dbuf + setprio ----
#define EXPC 0.18033688011f   // 0.125 * log2(e)

struct AttnState {
  f32x4 o[4];
  float l;
};

template <bool MASKED>
__device__ __forceinline__ void attn_tile_compute(
    int q0, int kt, bf16x8 qf0, bf16x8 qf1,
    const bf16x8 kf0[4], const bf16x8 kf1[4],
    const bf16x8 vf0[4], const bf16x8 vf1[4],
    AttnState& st, int lrow, int quad) {
  f32x4 s[4];
  __builtin_amdgcn_s_setprio(1);
  #pragma unroll
  for (int c = 0; c < 4; ++c) {
    f32x4 z = (f32x4){0.f, 0.f, 0.f, 0.f};
    z = __builtin_amdgcn_mfma_f32_16x16x32_bf16(kf0[c], qf0, z, 0, 0, 0);
    z = __builtin_amdgcn_mfma_f32_16x16x32_bf16(kf1[c], qf1, z, 0, 0, 0);
    s[c] = z;
  }
  __builtin_amdgcn_s_setprio(0);
  int q = q0 + lrow;
  unsigned w0[4], w1[4];   // W[c][0], W[c][1]: packed bf16 pairs, keys 16c+4*quad+{0,1},{2,3}
  #pragma unroll
  for (int c = 0; c < 4; ++c) {
    float pv[4];
    #pragma unroll
    for (int e = 0; e < 4; ++e) {
      float v = __builtin_amdgcn_exp2f(s[c][e] * EXPC);
      if (MASKED) {
        int key = kt + c * 16 + quad * 4 + e;
        v = (key <= q) ? v : 0.f;
      }
      pv[e] = v;
      st.l += v;
    }
    w0[c] = __builtin_amdgcn_perm(fbits(pv[1]), fbits(pv[0]), 0x07060302u);
    w1[c] = __builtin_amdgcn_perm(fbits(pv[3]), fbits(pv[2]), 0x07060302u);
  }

  // redistribute: pair (W[c], W[c+1]) -> permlane32_swap + permlane16_swap.
  unsigned a0 = w0[0], b0 = w0[1]; pswap32(a0, b0); pswap16(a0, b0);
  unsigned a1 = w1[0], b1 = w1[1]; pswap32(a1, b1); pswap16(a1, b1);
  unsigned c0 = w0[2], d0 = w0[3]; pswap32(c0, d0); pswap16(c0, d0);
  unsigned c1 = w1[2], d1 = w1[3]; pswap32(c1, d1); pswap16(c1, d1);
  union { uint32x4 u; bf16x8 b; } P0, P1;
  P0.u = (uint32x4){a0, a1, b0, b1};   // keys 8*quad+0..7   (A-frag, k=0..31)
  P1.u = (uint32x4){c0, c1, d0, d1};   // keys 32+8*quad+0..7 (A-frag, k=32..63)

  __builtin_amdgcn_s_setprio(1);
  #pragma unroll
  for (int dt = 0; dt < 4; ++dt) {
    st.o[dt] = __builtin_amdgcn_mfma_f32_16x16x32_bf16(P0.b, vf0[dt], st.o[dt], 0, 0, 0);
    st.o[dt] = __builtin_amdgcn_mfma_f32_16x16x32_bf16(P1.b, vf1[dt], st.o[dt], 0, 0, 0);
  }
  __builtin_amdgcn_s_setprio(0);
}

__global__ __launch_bounds__(256, 2) void attn_mfma(const ushort* __restrict__ Q,
                                                    const ushort* __restrict__ Kmat,
                                                    const ushort* __restrict__ Vt,
                                                    ushort* __restrict__ ctx) {
  __shared__ __align__(16) ushort Ks[2][64 * 72];    // [key][d]
  __shared__ __align__(16) ushort Vs[2][64 * 72];    // [d][key]
  int t = threadIdx.x;
  int lane = t & 63, wave = t >> 6;
  int lrow = lane & 15, quad = lane >> 4;
  int n = blockIdx.x;                  // 0..1023
  int qt = 31 - (n >> 5);              // heavy tiles dispatch first
  int bh = n & 31;                     // same head -> same XCD (n%8 == bh%8)
  const ushort* Kb = Kmat + (size_t)bh * S_ * HD;
  const ushort* Vb = Vt + (size_t)bh * HD * S_;
  int b = bh >> 4, h = bh & 15;

  int r0 = t >> 3, s0 = (t & 7) * 8;              // chunk t
  int r1 = (t + 256) >> 3, s1 = s0;               // chunk t+256

  int q0 = qt * 64 + wave * 16;
  const ushort* Qp = Q + ((size_t)bh * S_ + q0) * HD;
  bf16x8 qf0 = *(const bf16x8*)(Qp + (size_t)lrow * HD + quad * 8);
  bf16x8 qf1 = *(const bf16x8*)(Qp + (size_t)lrow * HD + 32 + quad * 8);

  AttnState st;
  #pragma unroll
  for (int i = 0; i < 4; ++i) st.o[i] = (f32x4){0.f, 0.f, 0.f, 0.f};
  st.l = 0.f;

  int kend = qt * 64;

  {
    uint4 ka = *(const uint4*)(Kb + (size_t)r0 * HD + s0);
    uint4 kb2 = *(const uint4*)(Kb + (size_t)r1 * HD + s1);
    uint4 va = *(const uint4*)(Vb + (size_t)r0 * S_ + s0);
    uint4 vb2 = *(const uint4*)(Vb + (size_t)r1 * S_ + s1);
    *(uint4*)(Ks[0] + r0 * 72 + s0) = ka;
    *(uint4*)(Ks[0] + r1 * 72 + s1) = kb2;
    *(uint4*)(Vs[0] + r0 * 72 + s0) = va;
    *(uint4*)(Vs[0] + r1 * 72 + s1) = vb2;
  }
  __syncthreads();

  for (int kt = 0; kt <= kend; kt += 64) {
    int cur = (kt >> 6) & 1, nxt = cur ^ 1;
    bool has_next = (kt < kend);

    uint4 ka, kb2, va, vb2;
    if (has_next) {
      int ktn = kt + 64;
      ka  = *(const uint4*)(Kb + (size_t)(ktn + r0) * HD + s0);
      kb2 = *(const uint4*)(Kb + (size_t)(ktn + r1) * HD + s1);
      va  = *(const uint4*)(Vb + (size_t)r0 * S_ + ktn + s0);
      vb2 = *(const uint4*)(Vb + (size_t)r1 * S_ + ktn + s1);
    }

    bf16x8 kf0[4], kf1[4], vf0[4], vf1[4];
    #pragma unroll
    for (int c2 = 0; c2 < 4; ++c2) {
      const ushort* kr = Ks[cur] + (c2 * 16 + lrow) * 72;
      kf0[c2] = *(const bf16x8*)(kr + quad * 8);
      kf1[c2] = *(const bf16x8*)(kr + 32 + quad * 8);
      const ushort* vr = Vs[cur] + (c2 * 16 + lrow) * 72;
      vf0[c2] = *(const bf16x8*)(vr + quad * 8);
      vf1[c2] = *(const bf16x8*)(vr + 32 + quad * 8);
    }

    if (kt < kend)
      attn_tile_compute<false>(q0, kt, qf0, qf1, kf0, kf1, vf0, vf1, st, lrow, quad);
    else
      attn_tile_compute<true>(q0, kt, qf0, qf1, kf0, kf1, vf0, vf1, st, lrow, quad);

    if (has_next) {
      *(uint4*)(Ks[nxt] + r0 * 72 + s0) = ka;
      *(uint4*)(Ks[nxt] + r1 * 72 + s1) = kb2;
      *(uint4*)(Vs[nxt] + r0 * 72 + s0) = va;
      *(uint4*)(Vs[nxt] + r1 * 72 + s1) = vb2;
    }
    __syncthreads();
  }

  {
    float l = st.l;
    l += __shfl_xor(l, 16);
    l += __shfl_xor(l, 32);
    float rl = 1.0f / l;
    #pragma unroll
    for (int e = 0; e < 4; ++e) {
      float rinv = __shfl(rl, quad * 4 + e);
      int q = q0 + quad * 4 + e;
      #pragma unroll
      for (int dt = 0; dt < 4; ++dt)
        ctx[((size_t)b * S_ + q) * DM + h * HD + dt * 16 + lrow] = f2bf(st.o[dt][e] * rinv);
    }
  }
}

// ---------------- launch ----------------
extern "C" void kernel_launch(void* const* d_in, const int* in_sizes, int n_in,
                              void* d_out, int out_size, void* d_ws, size_t ws_size,
                              hipStream_t stream) {
  const float* x  = (const float*)d_in[0];
  const float* Wq = (const float*)d_in[1];
  const float* Wk = (const float*)d_in[2];
  const float* Wv = (const float*)d_in[3];
  const float* Wo = (const float*)d_in[4];
  float* out = (float*)d_out;
  ushort* ws = (ushort*)d_ws;

  ushort* xb  = ws;                                   // 4M elem bf16 x
  ushort* wt  = xb + (size_t)M_ * DM;                 // 4 x 1M elem (Wq^T,Wk^T,Wv^T,Wo^T) bf16
  ushort* qkv = wt + (size_t)4 * DM * DM;             // Q,K [b,h,s,d]; V^T [b,h,d,s] bf16
  ushort* ctx = qkv + (size_t)3 * M_ * DM;            // 4M elem [B,S,DM] bf16

  cvt_prep<<<dim3(16, 16, 5), dim3(64, 4), 0, stream>>>(x, Wq, Wk, Wv, Wo, wt, xb);
  gemm_qkv<<<dim3(DM / 64, M_ / 128), 256, 0, stream>>>(xb, wt, qkv);
  attn_mfma<<<dim3(32 * B_ * NH), 256, 0, stream>>>(qkv, qkv + (size_t)M_ * DM,
                                                    qkv + (size_t)2 * M_ * DM, ctx);
  gemm_out<<<dim3(DM / 64, M_ / 128), 256, 0, stream>>>(ctx, wt + (size_t)3 * DM * DM, out);
}

// Round 17
// 170.488 us; speedup vs baseline: 1.0049x; 1.0049x over previous
//
#include <hip/hip_runtime.h>
#include <hip/hip_bf16.h>

#define DM 1024
#define NH 16
#define HD 64
#define B_ 2
#define S_ 2048
#define M_ (B_*S_)   // 4096

typedef __attribute__((ext_vector_type(8))) short bf16x8;
typedef __attribute__((ext_vector_type(4))) float f32x4;
typedef __attribute__((ext_vector_type(4))) unsigned uint32x4;
typedef __attribute__((ext_vector_type(2))) unsigned uint32x2;

__device__ __forceinline__ float bf2f(ushort u) {
  union { unsigned u32; float f; } c; c.u32 = ((unsigned)u) << 16; return c.f;
}
__device__ __forceinline__ ushort f2bf(float f) {
  union { float f; unsigned u32; } c; c.f = f;
  unsigned u = c.u32;
  unsigned r = (u + 0x7fffu + ((u >> 16) & 1u)) >> 16;
  return (ushort)r;
}
__device__ __forceinline__ unsigned fbits(float f) {
  union { float f; unsigned u; } c; c.f = f; return c.u;
}

// async global->LDS, 16 B per lane; LDS dest = wave-uniform base + lane*16
__device__ __forceinline__ void async16(const ushort* g, ushort* l) {
  __builtin_amdgcn_global_load_lds((const __attribute__((address_space(1))) void*)g,
                                   (__attribute__((address_space(3))) void*)l, 16, 0, 0);
}

// gfx950 cross-lane swaps via BUILTINS (not inline asm): permlane has a VALU-write ->
// permlane-read hazard requiring compiler-inserted wait states; the hazard recognizer
// can't see into inline asm (v9/v10 raw-asm miscompute; v11 builtins fixed it).
__device__ __forceinline__ void pswap32(unsigned& a, unsigned& b) {
  uint32x2 r = __builtin_amdgcn_permlane32_swap(a, b, false, false);
  a = r[0]; b = r[1];
}
__device__ __forceinline__ void pswap16(unsigned& a, unsigned& b) {
  uint32x2 r = __builtin_amdgcn_permlane16_swap(a, b, false, false);
  a = r[0]; b = r[1];
}

// ---- fused prep: z<4 -> fp32 W[k][n] -> bf16 Wt[n][k]; z==4 -> fp32 x -> bf16 ----
__global__ void cvt_prep(const float* __restrict__ x, const float* __restrict__ W0,
                         const float* __restrict__ W1, const float* __restrict__ W2,
                         const float* __restrict__ W3, ushort* __restrict__ wt,
                         ushort* __restrict__ xb) {
  __shared__ float tile[64][65];
  int z = blockIdx.z;
  int tx = threadIdx.x, ty = threadIdx.y;   // block (64,4)
  if (z == 4) {
    int tid = ty * 64 + tx;
    size_t base4 = ((size_t)blockIdx.y * 16 + blockIdx.x) * 4096;  // float4 units
    const float4* xv = (const float4*)x;
    ushort4* ov = (ushort4*)xb;
    #pragma unroll
    for (int k = 0; k < 16; ++k) {
      float4 v = xv[base4 + k * 256 + tid];
      ushort4 o;
      o.x = f2bf(v.x); o.y = f2bf(v.y); o.z = f2bf(v.z); o.w = f2bf(v.w);
      ov[base4 + k * 256 + tid] = o;
    }
    return;
  }
  const float* W = (z == 0) ? W0 : (z == 1) ? W1 : (z == 2) ? W2 : W3;
  ushort* Wt = wt + (size_t)z * (DM * DM);
  int c0 = blockIdx.x * 64, r0 = blockIdx.y * 64;
  #pragma unroll
  for (int i = ty; i < 64; i += 4) tile[i][tx] = W[(size_t)(r0 + i) * DM + c0 + tx];
  __syncthreads();
  #pragma unroll
  for (int i = ty; i < 64; i += 4) Wt[(size_t)(c0 + i) * DM + r0 + tx] = f2bf(tile[tx][i]);
}

// ---------------- MFMA GEMM body (used by gemm_out, MODE 0 only) ----------------
template <int MODE, int BN>
__device__ __forceinline__ void gemm_body(const ushort* __restrict__ A,
                                          const ushort* __restrict__ Bt,
                                          ushort* __restrict__ Cb,
                                          float* __restrict__ Cf,
                                          ushort* As, ushort* Bs, ushort* Ts) {
  const int K = DM;
  constexpr int CN = BN / 32;                   // n-frags per wave
  int m0 = blockIdx.y * 128;
  int n0 = blockIdx.x * BN;
  int t = threadIdx.x;
  int lane = t & 63, wave = t >> 6;
  int wm = (wave >> 1) * 64, wn = (wave & 1) * (BN / 2);
  int lrow = lane & 15, quad = lane >> 4;

  int Ra = wave * 32;                           // A rows staged by this wave
  int Rb = wave * (BN / 4);                     // B rows staged by this wave
  int srow = lane >> 2, scol = (lane & 3) * 8;  // per-lane 16B chunk within 16-row group

  f32x4 acc[4][CN];
  #pragma unroll
  for (int r = 0; r < 4; ++r)
    #pragma unroll
    for (int c = 0; c < CN; ++c) acc[r][c] = (f32x4){0.f, 0.f, 0.f, 0.f};

  for (int k0 = 0; k0 < K; k0 += 32) {
    const ushort* ga = A + (size_t)(m0 + Ra + srow) * K + k0 + scol;
    const ushort* gb = Bt + (size_t)(n0 + Rb + srow) * K + k0 + scol;
    async16(ga,          As + Ra * 32);
    async16(ga + 16 * K, As + (Ra + 16) * 32);
    async16(gb,          Bs + Rb * 32);
    if (BN == 128) async16(gb + 16 * K, Bs + (Rb + 16) * 32);
    __syncthreads();

    bf16x8 af[4], bfr[CN];
    #pragma unroll
    for (int r = 0; r < 4; ++r)
      af[r] = *(const bf16x8*)(As + (wm + r * 16 + lrow) * 32 + quad * 8);
    #pragma unroll
    for (int c = 0; c < CN; ++c)
      bfr[c] = *(const bf16x8*)(Bs + (wn + c * 16 + lrow) * 32 + quad * 8);
    #pragma unroll
    for (int r = 0; r < 4; ++r)
      #pragma unroll
      for (int c = 0; c < CN; ++c)
        acc[r][c] = __builtin_amdgcn_mfma_f32_16x16x32_bf16(af[r], bfr[c], acc[r][c], 0, 0, 0);
    __syncthreads();
  }

  // epilogue: C/D layout col=lane&15, row=quad*4+e
  #pragma unroll
  for (int r = 0; r < 4; ++r) {
    #pragma unroll
    for (int c = 0; c < CN; ++c) {
      #pragma unroll
      for (int e = 0; e < 4; ++e) {
        int m = m0 + wm + r * 16 + quad * 4 + e;
        int n = n0 + wn + c * 16 + lrow;
        if (MODE == 0) {
          Cf[(size_t)m * DM + n] = acc[r][c][e];
        }
      }
    }
  }
}

// ---------------- fused QKV GEMM ----------------
// v20: v19's fused structure (A staged once per K-step, reused for 3 weight panels;
// FETCH 35.9->~16MB) + __launch_bounds__(256,3). v19 post-mortem: fused at (256,2)
// landed ~150-170 VGPR -> only 2 blocks/CU (8 waves/CU) vs v18-qkv's 3 blocks/CU
// (VGPR 60) — the TLP loss ate the instruction savings (171.3 vs 168.5 total).
// (256,3) caps VGPR at 170: acc 96 + af 16 + addr/temps ~40 = ~150 fits -> no spill
// expected (mild constraint, NOT v8's 96->64 squeeze). LDS 20.5KB x3 = 61.5KB fine.
__global__ __launch_bounds__(256, 3) void gemm_qkv(const ushort* __restrict__ A,
                                                   const ushort* __restrict__ wt,
                                                   ushort* __restrict__ qkv) {
  __shared__ __align__(16) ushort smem[10240];
  ushort* As = smem;
  ushort* Ts = smem;
  const int K = DM;
  int m0 = blockIdx.y * 128;
  int n0 = blockIdx.x * 64;
  int t = threadIdx.x;
  int lane = t & 63, wave = t >> 6;
  int wm = (wave >> 1) * 64, wn = (wave & 1) * 32;
  int lrow = lane & 15, quad = lane >> 4;
  int Ra = wave * 32;                           // A rows staged by this wave
  int Rb = wave * 16;                           // B rows staged by this wave (per z)
  int srow = lane >> 2, scol = (lane & 3) * 8;

  f32x4 acc[3][4][2];
  #pragma unroll
  for (int z = 0; z < 3; ++z)
    #pragma unroll
    for (int r = 0; r < 4; ++r)
      #pragma unroll
      for (int c = 0; c < 2; ++c) acc[z][r][c] = (f32x4){0.f, 0.f, 0.f, 0.f};

  for (int k0 = 0; k0 < K; k0 += 32) {
    const ushort* ga = A + (size_t)(m0 + Ra + srow) * K + k0 + scol;
    async16(ga,          As + Ra * 32);
    async16(ga + 16 * K, As + (Ra + 16) * 32);
    #pragma unroll
    for (int z = 0; z < 3; ++z) {
      const ushort* gb = wt + (size_t)z * (DM * DM) + (size_t)(n0 + Rb + srow) * K + k0 + scol;
      async16(gb, smem + 4096 + z * 2048 + Rb * 32);
    }
    __syncthreads();

    bf16x8 af[4];
    #pragma unroll
    for (int r = 0; r < 4; ++r)
      af[r] = *(const bf16x8*)(As + (wm + r * 16 + lrow) * 32 + quad * 8);
    #pragma unroll
    for (int z = 0; z < 3; ++z) {
      bf16x8 bfr[2];
      #pragma unroll
      for (int c = 0; c < 2; ++c)
        bfr[c] = *(const bf16x8*)(smem + 4096 + z * 2048 + (wn + c * 16 + lrow) * 32 + quad * 8);
      #pragma unroll
      for (int r = 0; r < 4; ++r)
        #pragma unroll
        for (int c = 0; c < 2; ++c)
          acc[z][r][c] = __builtin_amdgcn_mfma_f32_16x16x32_bf16(af[r], bfr[c], acc[z][r][c], 0, 0, 0);
    }
    __syncthreads();
  }

  // ---- epilogue z=0,1 (Q,K): head layout [b,h,s,d] ----
  #pragma unroll
  for (int z = 0; z < 2; ++z) {
    ushort* Cz = qkv + (size_t)z * ((size_t)M_ * DM);
    #pragma unroll
    for (int r = 0; r < 4; ++r) {
      #pragma unroll
      for (int c = 0; c < 2; ++c) {
        #pragma unroll
        for (int e = 0; e < 4; ++e) {
          int m = m0 + wm + r * 16 + quad * 4 + e;
          int n = n0 + wn + c * 16 + lrow;
          int b = m >> 11, s = m & 2047, h = n >> 6, d = n & 63;
          Cz[(((size_t)(b * NH + h)) * S_ + s) * HD + d] = f2bf(acc[z][r][c][e]);
        }
      }
    }
  }

  // ---- epilogue z=2 (V): V^T [b,h,d,s] via LDS transpose, two half-passes ----
  {
    ushort* Cb = qkv + (size_t)2 * ((size_t)M_ * DM);
    int bb = m0 >> 11;
    int s0base = m0 & 2047;
    int h2 = n0 >> 6;
    #pragma unroll
    for (int H = 0; H < 2; ++H) {
      __syncthreads();            // Ts reuse guard (and As/Bs death guard on H=0)
      if ((wave >> 1) == H) {
        #pragma unroll
        for (int r = 0; r < 4; ++r)
          #pragma unroll
          for (int c = 0; c < 2; ++c) {
            uint2 pk;
            pk.x = (unsigned)f2bf(acc[2][r][c][0]) | ((unsigned)f2bf(acc[2][r][c][1]) << 16);
            pk.y = (unsigned)f2bf(acc[2][r][c][2]) | ((unsigned)f2bf(acc[2][r][c][3]) << 16);
            *(uint2*)(Ts + (wn + c * 16 + lrow) * 72 + r * 16 + quad * 4) = pk;
          }
      }
      __syncthreads();
      #pragma unroll
      for (int i = 0; i < 2; ++i) {
        int id = t + i * 256;            // 0..511
        int nn = id >> 3, col = (id & 7) * 8;
        uint4 v = *(const uint4*)(Ts + nn * 72 + col);
        size_t dst = (((size_t)(bb * NH + h2)) * HD + nn) * (size_t)S_ + s0base + H * 64 + col;
        *(uint4*)(Cb + dst) = v;
      }
    }
  }
}

// 128x64 tiles -> grid 512, 12 KB LDS, 3 blocks/CU target
__global__ __launch_bounds__(256, 3) void gemm_out(const ushort* __restrict__ A,
                                                   const ushort* __restrict__ wt,
                                                   float* __restrict__ C) {
  __shared__ __align__(16) ushort As[128 * 32];
  __shared__ __align__(16) ushort Bs[64 * 32];
  gemm_body<0, 64>(A, wt, nullptr, C, As, Bs, nullptr);
}

// ---------------- MFMA flash attention v18 (unchanged): single-barrier dbuf + setprio ----
#define EXPC 0.18033688011f   // 0.125 * log2(e)

struct AttnState {
  f32x4 o[4];
  float l;
};

template <bool MASKED>
__device__ __forceinline__ void attn_tile_compute(
    int q0, int kt, bf16x8 qf0, bf16x8 qf1,
    const bf16x8 kf0[4], const bf16x8 kf1[4],
    const bf16x8 vf0[4], const bf16x8 vf1[4],
    AttnState& st, int lrow, int quad) {
  f32x4 s[4];
  __builtin_amdgcn_s_setprio(1);
  #pragma unroll
  for (int c = 0; c < 4; ++c) {
    f32x4 z = (f32x4){0.f, 0.f, 0.f, 0.f};
    z = __builtin_amdgcn_mfma_f32_16x16x32_bf16(kf0[c], qf0, z, 0, 0, 0);
    z = __builtin_amdgcn_mfma_f32_16x16x32_bf16(kf1[c], qf1, z, 0, 0, 0);
    s[c] = z;
  }
  __builtin_amdgcn_s_setprio(0);
  int q = q0 + lrow;
  unsigned w0[4], w1[4];   // W[c][0], W[c][1]: packed bf16 pairs, keys 16c+4*quad+{0,1},{2,3}
  #pragma unroll
  for (int c = 0; c < 4; ++c) {
    float pv[4];
    #pragma unroll
    for (int e = 0; e < 4; ++e) {
      float v = __builtin_amdgcn_exp2f(s[c][e] * EXPC);
      if (MASKED) {
        int key = kt + c * 16 + quad * 4 + e;
        v = (key <= q) ? v : 0.f;
      }
      pv[e] = v;
      st.l += v;
    }
    w0[c] = __builtin_amdgcn_perm(fbits(pv[1]), fbits(pv[0]), 0x07060302u);
    w1[c] = __builtin_amdgcn_perm(fbits(pv[3]), fbits(pv[2]), 0x07060302u);
  }

  // redistribute: pair (W[c], W[c+1]) -> permlane32_swap + permlane16_swap.
  unsigned a0 = w0[0], b0 = w0[1]; pswap32(a0, b0); pswap16(a0, b0);
  unsigned a1 = w1[0], b1 = w1[1]; pswap32(a1, b1); pswap16(a1, b1);
  unsigned c0 = w0[2], d0 = w0[3]; pswap32(c0, d0); pswap16(c0, d0);
  unsigned c1 = w1[2], d1 = w1[3]; pswap32(c1, d1); pswap16(c1, d1);
  union { uint32x4 u; bf16x8 b; } P0, P1;
  P0.u = (uint32x4){a0, a1, b0, b1};   // keys 8*quad+0..7   (A-frag, k=0..31)
  P1.u = (uint32x4){c0, c1, d0, d1};   // keys 32+8*quad+0..7 (A-frag, k=32..63)

  __builtin_amdgcn_s_setprio(1);
  #pragma unroll
  for (int dt = 0; dt < 4; ++dt) {
    st.o[dt] = __builtin_amdgcn_mfma_f32_16x16x32_bf16(P0.b, vf0[dt], st.o[dt], 0, 0, 0);
    st.o[dt] = __builtin_amdgcn_mfma_f32_16x16x32_bf16(P1.b, vf1[dt], st.o[dt], 0, 0, 0);
  }
  __builtin_amdgcn_s_setprio(0);
}

__global__ __launch_bounds__(256, 2) void attn_mfma(const ushort* __restrict__ Q,
                                                    const ushort* __restrict__ Kmat,
                                                    const ushort* __restrict__ Vt,
                                                    ushort* __restrict__ ctx) {
  __shared__ __align__(16) ushort Ks[2][64 * 72];    // [key][d]
  __shared__ __align__(16) ushort Vs[2][64 * 72];    // [d][key]
  int t = threadIdx.x;
  int lane = t & 63, wave = t >> 6;
  int lrow = lane & 15, quad = lane >> 4;
  int n = blockIdx.x;                  // 0..1023
  int qt = 31 - (n >> 5);              // heavy tiles dispatch first
  int bh = n & 31;                     // same head -> same XCD (n%8 == bh%8)
  const ushort* Kb = Kmat + (size_t)bh * S_ * HD;
  const ushort* Vb = Vt + (size_t)bh * HD * S_;
  int b = bh >> 4, h = bh & 15;

  int r0 = t >> 3, s0 = (t & 7) * 8;              // chunk t
  int r1 = (t + 256) >> 3, s1 = s0;               // chunk t+256

  int q0 = qt * 64 + wave * 16;
  const ushort* Qp = Q + ((size_t)bh * S_ + q0) * HD;
  bf16x8 qf0 = *(const bf16x8*)(Qp + (size_t)lrow * HD + quad * 8);
  bf16x8 qf1 = *(const bf16x8*)(Qp + (size_t)lrow * HD + 32 + quad * 8);

  AttnState st;
  #pragma unroll
  for (int i = 0; i < 4; ++i) st.o[i] = (f32x4){0.f, 0.f, 0.f, 0.f};
  st.l = 0.f;

  int kend = qt * 64;

  {
    uint4 ka = *(const uint4*)(Kb + (size_t)r0 * HD + s0);
    uint4 kb2 = *(const uint4*)(Kb + (size_t)r1 * HD + s1);
    uint4 va = *(const uint4*)(Vb + (size_t)r0 * S_ + s0);
    uint4 vb2 = *(const uint4*)(Vb + (size_t)r1 * S_ + s1);
    *(uint4*)(Ks[0] + r0 * 72 + s0) = ka;
    *(uint4*)(Ks[0] + r1 * 72 + s1) = kb2;
    *(uint4*)(Vs[0] + r0 * 72 + s0) = va;
    *(uint4*)(Vs[0] + r1 * 72 + s1) = vb2;
  }
  __syncthreads();

  for (int kt = 0; kt <= kend; kt += 64) {
    int cur = (kt >> 6) & 1, nxt = cur ^ 1;
    bool has_next = (kt < kend);

    uint4 ka, kb2, va, vb2;
    if (has_next) {
      int ktn = kt + 64;
      ka  = *(const uint4*)(Kb + (size_t)(ktn + r0) * HD + s0);
      kb2 = *(const uint4*)(Kb + (size_t)(ktn + r1) * HD + s1);
      va  = *(const uint4*)(Vb + (size_t)r0 * S_ + ktn + s0);
      vb2 = *(const uint4*)(Vb + (size_t)r1 * S_ + ktn + s1);
    }

    bf16x8 kf0[4], kf1[4], vf0[4], vf1[4];
    #pragma unroll
    for (int c2 = 0; c2 < 4; ++c2) {
      const ushort* kr = Ks[cur] + (c2 * 16 + lrow) * 72;
      kf0[c2] = *(const bf16x8*)(kr + quad * 8);
      kf1[c2] = *(const bf16x8*)(kr + 32 + quad * 8);
      const ushort* vr = Vs[cur] + (c2 * 16 + lrow) * 72;
      vf0[c2] = *(const bf16x8*)(vr + quad * 8);
      vf1[c2] = *(const bf16x8*)(vr + 32 + quad * 8);
    }

    if (kt < kend)
      attn_tile_compute<false>(q0, kt, qf0, qf1, kf0, kf1, vf0, vf1, st, lrow, quad);
    else
      attn_tile_compute<true>(q0, kt, qf0, qf1, kf0, kf1, vf0, vf1, st, lrow, quad);

    if (has_next) {
      *(uint4*)(Ks[nxt] + r0 * 72 + s0) = ka;
      *(uint4*)(Ks[nxt] + r1 * 72 + s1) = kb2;
      *(uint4*)(Vs[nxt] + r0 * 72 + s0) = va;
      *(uint4*)(Vs[nxt] + r1 * 72 + s1) = vb2;
    }
    __syncthreads();
  }

  {
    float l = st.l;
    l += __shfl_xor(l, 16);
    l += __shfl_xor(l, 32);
    float rl = 1.0f / l;
    #pragma unroll
    for (int e = 0; e < 4; ++e) {
      float rinv = __shfl(rl, quad * 4 + e);
      int q = q0 + quad * 4 + e;
      #pragma unroll
      for (int dt = 0; dt < 4; ++dt)
        ctx[((size_t)b * S_ + q) * DM + h * HD + dt * 16 + lrow] = f2bf(st.o[dt][e] * rinv);
    }
  }
}

// ---------------- launch ----------------
extern "C" void kernel_launch(void* const* d_in, const int* in_sizes, int n_in,
                              void* d_out, int out_size, void* d_ws, size_t ws_size,
                              hipStream_t stream) {
  const float* x  = (const float*)d_in[0];
  const float* Wq = (const float*)d_in[1];
  const float* Wk = (const float*)d_in[2];
  const float* Wv = (const float*)d_in[3];
  const float* Wo = (const float*)d_in[4];
  float* out = (float*)d_out;
  ushort* ws = (ushort*)d_ws;

  ushort* xb  = ws;                                   // 4M elem bf16 x
  ushort* wt  = xb + (size_t)M_ * DM;                 // 4 x 1M elem (Wq^T,Wk^T,Wv^T,Wo^T) bf16
  ushort* qkv = wt + (size_t)4 * DM * DM;             // Q,K [b,h,s,d]; V^T [b,h,d,s] bf16
  ushort* ctx = qkv + (size_t)3 * M_ * DM;            // 4M elem [B,S,DM] bf16

  cvt_prep<<<dim3(16, 16, 5), dim3(64, 4), 0, stream>>>(x, Wq, Wk, Wv, Wo, wt, xb);
  gemm_qkv<<<dim3(DM / 64, M_ / 128), 256, 0, stream>>>(xb, wt, qkv);
  attn_mfma<<<dim3(32 * B_ * NH), 256, 0, stream>>>(qkv, qkv + (size_t)M_ * DM,
                                                    qkv + (size_t)2 * M_ * DM, ctx);
  gemm_out<<<dim3(DM / 64, M_ / 128), 256, 0, stream>>>(ctx, wt + (size_t)3 * DM * DM, out);
}